// Round 11
// baseline (39.486 us; speedup 1.0000x reference)
//
#include <hip/hip_runtime.h>
#include <math.h>

#define B_ 4
#define T_ 512
#define C_ 128
#define HS_ 64

typedef float f4 __attribute__((ext_vector_type(4)));

// scale = C^-0.5
#define SCALE_ 0.08838834764831845f

// ---------------------------------------------------------------------------
// Kernel 1: prep.  x1 = x + pos_emb;  Aq = x1@W1q + b1;  AkT = (x1@W1k)^T;
// V = x@Wv.  256 blocks x 640 threads, block = 8 rows.  (unchanged, round 10)
// ---------------------------------------------------------------------------
__global__ __launch_bounds__(640) void k_prep(
    const float* __restrict__ x, const float* __restrict__ pos,
    const float* __restrict__ W1, const float* __restrict__ b1,
    const float* __restrict__ Wv,
    float* __restrict__ Aq, float* __restrict__ AkT, float* __restrict__ V)
{
    __shared__ float x1s[8 * 132];
    __shared__ float xs[8 * 132];
    const int t = threadIdx.x;
    const int row0 = blockIdx.x * 8;  // over B*T = 2048

    if (t < 256) {
        int r = t >> 5, cq = t & 31;
        int gr = row0 + r;
        f4 xv = *(const f4*)(x + gr * 128 + cq * 4);
        f4 pv = *(const f4*)(pos + (gr & 511) * 128 + cq * 4);
        *(f4*)&xs[r * 132 + cq * 4] = xv;
        *(f4*)&x1s[r * 132 + cq * 4] = xv + pv;
    }
    __syncthreads();

    const int q = t >> 3;   // 0..79 col-quad
    const int r = t & 7;    // row in tile

    const float* wbase;
    int wstr, col0;
    const float* xb;
    f4 binit = {0.f, 0.f, 0.f, 0.f};
    if (q < 32) {
        col0 = q * 4;
        wbase = W1 + 128 * 128 + col0;  // W1q rows (c-major)
        wstr = 128;
        xb = x1s;
        binit = *(const f4*)(b1 + col0);
    } else if (q < 64) {
        col0 = (q - 32) * 4;
        wbase = W1 + col0;  // W1k rows
        wstr = 128;
        xb = x1s;
    } else {
        col0 = (q - 64) * 4;
        wbase = Wv + col0;
        wstr = 64;
        xb = xs;
    }

    f4 acc = binit;
    const float* xr = xb + r * 132;
#pragma unroll 8
    for (int c = 0; c < 128; ++c) {
        f4 w = *(const f4*)(wbase + c * wstr);
        acc += xr[c] * w;
    }

    const int gr = row0 + r;
    if (q < 32) {
        *(f4*)(Aq + (size_t)gr * 128 + col0) = acc;
    } else if (q < 64) {
        const int bb = gr >> 9, j = gr & 511;
        float* base = AkT + ((size_t)bb * 128 + col0) * 512 + j;
        base[0]    = acc.x;
        base[512]  = acc.y;
        base[1024] = acc.z;
        base[1536] = acc.w;
    } else {
        *(f4*)(V + (size_t)gr * 64 + col0) = acc;
    }
}

// ---------------------------------------------------------------------------
// Kernel 2: fused S + per-window softmax partials. Block = (b, 16-row group G,
// 64-j window w); 4 waves x 4 rows. AkT window (32KB) + Aq rows (8KB) + W2
// staged in LDS ONCE per block -> each AkT/Aq byte fetched from L2 once per
// 16 rows (fused L2 traffic 240MB -> ~30MB). Inner loop: ak = LDS lane-read
// (2-way alias, free), aq/w2 = LDS broadcast, ZERO cross-lane ops.
// Per (row, window): flash partial (m, l, acc[64]) -> workspace.
// Blocks enumerate only causally-live (G, w) pairs: per batch
// sum_G ceil((G+1)/4) = 144; band n (=#windows) holds G in [4(n-1),4n).
// All waves execute both barriers; causally-dead rows write (-1e30, 0, 0).
// ---------------------------------------------------------------------------
__global__ __launch_bounds__(256) void k_fusedp(
    const float* __restrict__ Aq, const float* __restrict__ AkT,
    const float* __restrict__ V, const float* __restrict__ W2,
    float* __restrict__ pml, float* __restrict__ pacc)
{
    __shared__ float aks[128][64];    // [c][j-in-window] 32 KB
    __shared__ float aqs[16][128];    // 8 KB
    __shared__ float w2s[128];
    __shared__ float pbuf[4][4][64];  // [wave][row][j] 4 KB

    const int t = threadIdx.x;
    const int b = blockIdx.y;
    const int f = blockIdx.x;         // 0..143

    // decode band: n windows for G in [4(n-1), 4n); cum before band = 2n(n-1)
    int n = (int)((1.0f + sqrtf(1.0f + 2.0f * (float)f)) * 0.5f);
    while (2 * n * (n - 1) > f) --n;
    while (2 * n * (n + 1) <= f) ++n;
    const int rem = f - 2 * n * (n - 1);
    const int G = 4 * (n - 1) + rem / n;  // 0..31
    const int w = rem % n;                // window index
    const int j0 = w * 64;
    const int row0 = G * 16;

    // ---- stage AkT window, Aq rows, W2 ----
    const float* aktw = AkT + (size_t)b * 128 * 512 + j0;
    for (int idx = t; idx < 2048; idx += 256) {   // 128 c x 16 f4
        int c = idx >> 4, qq = idx & 15;
        *(f4*)&aks[c][qq * 4] = *(const f4*)(aktw + (size_t)c * 512 + qq * 4);
    }
    const float* aqg = Aq + (size_t)(b * 512 + row0) * 128;
    for (int idx = t; idx < 512; idx += 256) {    // 16 r x 32 f4
        int r = idx >> 5, cq = idx & 31;
        *(f4*)&aqs[r][cq * 4] = *(const f4*)(aqg + r * 128 + cq * 4);
    }
    if (t < 32) *(f4*)&w2s[t * 4] = *(const f4*)(W2 + t * 4);
    __syncthreads();

    const int w8 = t >> 6;
    const int lane = t & 63;
    const int rb = 4 * w8;            // row offset within group
    const int r0 = row0 + rb, r1 = r0 + 1, r2 = r0 + 2, r3 = r0 + 3;
    const int gj = j0 + lane;

    float m0 = -1e30f, m1 = -1e30f, m2 = -1e30f, m3 = -1e30f;
    float l0 = 0.f, l1 = 0.f, l2 = 0.f, l3 = 0.f;
    float a0 = 0.f, a1 = 0.f, a2 = 0.f, a3 = 0.f;

    if (r3 >= j0) {  // wave has at least one live row
        // ---- S over 128 c for 4 rows, 1 j per lane ----
        float s0 = 0.f, s1 = 0.f, s2 = 0.f, s3 = 0.f;
#pragma unroll 4
        for (int c = 0; c < 128; ++c) {
            const float ak = aks[c][lane];
            const float wv = w2s[c];
            s0 += fmaxf(ak + aqs[rb + 0][c], 0.f) * wv;
            s1 += fmaxf(ak + aqs[rb + 1][c], 0.f) * wv;
            s2 += fmaxf(ak + aqs[rb + 2][c], 0.f) * wv;
            s3 += fmaxf(ak + aqs[rb + 3][c], 0.f) * wv;
        }
        s0 = (gj <= r0) ? s0 * SCALE_ : -1e30f;
        s1 = (gj <= r1) ? s1 * SCALE_ : -1e30f;
        s2 = (gj <= r2) ? s2 * SCALE_ : -1e30f;
        s3 = (gj <= r3) ? s3 * SCALE_ : -1e30f;

        // ---- per-row window max / exp / sum ----
        float t0 = s0, t1 = s1, t2 = s2, t3 = s3;
#pragma unroll
        for (int off = 1; off < 64; off <<= 1) {
            t0 = fmaxf(t0, __shfl_xor(t0, off));
            t1 = fmaxf(t1, __shfl_xor(t1, off));
            t2 = fmaxf(t2, __shfl_xor(t2, off));
            t3 = fmaxf(t3, __shfl_xor(t3, off));
        }
        const float p0 = __expf(s0 - t0);
        const float p1 = __expf(s1 - t1);
        const float p2 = __expf(s2 - t2);
        const float p3 = __expf(s3 - t3);
        pbuf[w8][0][lane] = p0;
        pbuf[w8][1][lane] = p1;
        pbuf[w8][2][lane] = p2;
        pbuf[w8][3][lane] = p3;
        float u0 = p0, u1 = p1, u2 = p2, u3 = p3;
#pragma unroll
        for (int off = 1; off < 64; off <<= 1) {
            u0 += __shfl_xor(u0, off);
            u1 += __shfl_xor(u1, off);
            u2 += __shfl_xor(u2, off);
            u3 += __shfl_xor(u3, off);
        }

        // ---- PV over the window; lane = h; V loads shared by 4 rows ----
        const float* vt = V + ((size_t)b * 512 + j0) * 64 + lane;
        float b0 = 0.f, b1v = 0.f, b2v = 0.f, b3 = 0.f;
#pragma unroll 4
        for (int q4 = 0; q4 < 16; ++q4) {
            f4 q0 = *(const f4*)&pbuf[w8][0][q4 * 4];
            f4 q1 = *(const f4*)&pbuf[w8][1][q4 * 4];
            f4 q2 = *(const f4*)&pbuf[w8][2][q4 * 4];
            f4 q3 = *(const f4*)&pbuf[w8][3][q4 * 4];
            const float v0 = vt[(q4 * 4 + 0) * 64];
            const float v1 = vt[(q4 * 4 + 1) * 64];
            const float v2 = vt[(q4 * 4 + 2) * 64];
            const float v3 = vt[(q4 * 4 + 3) * 64];
            b0  += q0.x * v0 + q0.y * v1 + q0.z * v2 + q0.w * v3;
            b1v += q1.x * v0 + q1.y * v1 + q1.z * v2 + q1.w * v3;
            b2v += q2.x * v0 + q2.y * v1 + q2.z * v2 + q2.w * v3;
            b3  += q3.x * v0 + q3.y * v1 + q3.z * v2 + q3.w * v3;
        }

        // rows with r_i < j0 are causally dead: zero their partials
        const bool c0 = (r0 >= j0), c1 = (r1 >= j0), c2 = (r2 >= j0);
        m0 = c0 ? t0 : -1e30f;  l0 = c0 ? u0 : 0.f;  a0 = c0 ? b0 : 0.f;
        m1 = c1 ? t1 : -1e30f;  l1 = c1 ? u1 : 0.f;  a1 = c1 ? b1v : 0.f;
        m2 = c2 ? t2 : -1e30f;  l2 = c2 ? u2 : 0.f;  a2 = c2 ? b2v : 0.f;
        m3 = t3;                l3 = u3;             a3 = b3;
    }

    // ---- write partials: key = (global row)*8 + w ----
    const size_t k0 = ((size_t)(b * 512 + r0) * 8 + w);
    pacc[(k0 + 0 ) * 64 + lane] = a0;
    pacc[(k0 + 8 ) * 64 + lane] = a1;
    pacc[(k0 + 16) * 64 + lane] = a2;
    pacc[(k0 + 24) * 64 + lane] = a3;
    if (lane == 0) {
        pml[(k0 + 0 ) * 2] = m0;  pml[(k0 + 0 ) * 2 + 1] = l0;
        pml[(k0 + 8 ) * 2] = m1;  pml[(k0 + 8 ) * 2 + 1] = l1;
        pml[(k0 + 16) * 2] = m2;  pml[(k0 + 16) * 2 + 1] = l2;
        pml[(k0 + 24) * 2] = m3;  pml[(k0 + 24) * 2 + 1] = l3;
    }
}

// ---------------------------------------------------------------------------
// Kernel 3: merge. One wave per row; flash-combine its nw = row%T/64 + 1
// window partials. Reads only w <= i>>6 (always written by k_fusedp).
// ---------------------------------------------------------------------------
__global__ __launch_bounds__(256) void k_merge(
    const float* __restrict__ pml, const float* __restrict__ pacc,
    float* __restrict__ out)
{
    const int t = threadIdx.x;
    const int w8 = t >> 6, lane = t & 63;
    const int grow = blockIdx.x * 4 + w8;   // 0..2047
    const int i = grow & 511;
    const int nw = (i >> 6) + 1;
    const size_t base = (size_t)grow * 8;

    float ms = -1e30f;
    for (int w = 0; w < nw; ++w) ms = fmaxf(ms, pml[(base + w) * 2]);
    float num = 0.f, den = 0.f;
    for (int w = 0; w < nw; ++w) {
        const float e = __expf(pml[(base + w) * 2] - ms);
        den += pml[(base + w) * 2 + 1] * e;
        num += pacc[(base + w) * 64 + lane] * e;
    }
    out[(size_t)grow * 64 + lane] = num / den;
}

// ---------------------------------------------------------------------------
extern "C" void kernel_launch(void* const* d_in, const int* in_sizes, int n_in,
                              void* d_out, int out_size, void* d_ws, size_t ws_size,
                              hipStream_t stream)
{
    const float* x   = (const float*)d_in[0];
    const float* pos = (const float*)d_in[1];
    const float* W1  = (const float*)d_in[2];
    const float* b1  = (const float*)d_in[3];
    const float* W2  = (const float*)d_in[4];
    const float* b2  = (const float*)d_in[5];  (void)b2;  // cancels in softmax
    const float* Wv  = (const float*)d_in[6];
    float* out = (float*)d_out;
    float* ws = (float*)d_ws;

    float* Aq   = ws;                 // B*T*C   = 262144
    float* AkT  = ws + 262144;        // B*C*T   = 262144 (transposed)
    float* V    = ws + 524288;        // B*T*HS  = 131072
    float* pml  = ws + 655360;        // 2048*8*2  = 32768
    float* pacc = ws + 688128;        // 2048*8*64 = 1048576

    k_prep<<<dim3(256), dim3(640), 0, stream>>>(x, pos, W1, b1, Wv, Aq, AkT, V);
    k_fusedp<<<dim3(144, B_), dim3(256), 0, stream>>>(Aq, AkT, V, W2, pml, pacc);
    k_merge<<<dim3(512), dim3(256), 0, stream>>>(pml, pacc, out);
}